// Round 1
// 3063.552 us; speedup vs baseline: 3.6305x; 3.6305x over previous
//
#include <hip/hip_runtime.h>
#include <math.h>

#define L_ 6
#define H_ 8
#define D_HD 64
#define E_ 512
#define V_ 32000
#define S_ 2048
#define B_ 2
#define M_ (B_*S_)   // 4096 rows

typedef float  floatx4 __attribute__((ext_vector_type(4)));
typedef short  shortx8 __attribute__((ext_vector_type(8)));
typedef short  shortx4 __attribute__((ext_vector_type(4)));

__device__ __forceinline__ short f2bf(float f){
  unsigned u = __builtin_bit_cast(unsigned, f);
  u += 0x7FFFu + ((u >> 16) & 1u);   // round-to-nearest-even
  return (short)(u >> 16);
}
__device__ __forceinline__ float bf2f(short s){
  unsigned u = ((unsigned)(unsigned short)s) << 16;
  return __builtin_bit_cast(float, u);
}
__device__ __forceinline__ float gelu_exact(float x){
  return 0.5f * x * (1.0f + erff(x * 0.70710678118654752440f));
}

// XOR bank swizzle for 128B-row LDS tiles: spreads the 16-lanes-same-column
// ds_read_b128 pattern across 8 distinct 16B slots (G4: row-major D=128 trap).
__device__ __forceinline__ char* lds_at(void* base, int row, int colByte){
  return (char*)base + (((row << 7) + colByte) ^ ((row & 7) << 4));
}

// ---------------- embedding: x = tok_emb[id]/sqrt(E) + pos_emb[s] ----------
__global__ __launch_bounds__(128) void embed_k(const int* __restrict__ ids,
                                               const float* __restrict__ tok,
                                               const float* __restrict__ pos,
                                               float* __restrict__ x){
  int row = blockIdx.x;            // 0..M_-1  (= b*S + s)
  int s   = row & (S_ - 1);
  int id  = ids[row];
  const float4* te = (const float4*)(tok + (long long)id * E_);
  const float4* pe = (const float4*)(pos + (long long)s  * E_);
  float4 a = te[threadIdx.x];
  float4 b = pe[threadIdx.x];
  const float isq = 0.04419417382415922f;  // 1/sqrt(512)
  float4 o = { a.x*isq + b.x, a.y*isq + b.y, a.z*isq + b.z, a.w*isq + b.w };
  ((float4*)(x + (long long)row * E_))[threadIdx.x] = o;
}

// ---------------- LayerNorm (no bias, eps=1e-6), one block per row ---------
__global__ __launch_bounds__(128) void ln_k(const float* __restrict__ x,
                                            const float* __restrict__ g,
                                            float* __restrict__ out){
  int row = blockIdx.x, tid = threadIdx.x;
  int lane = tid & 63, wid = tid >> 6;
  float4 v = ((const float4*)(x + (long long)row * E_))[tid];
  float s  = v.x + v.y + v.z + v.w;
  float sq = v.x*v.x + v.y*v.y + v.z*v.z + v.w*v.w;
  #pragma unroll
  for(int off = 32; off > 0; off >>= 1){
    s  += __shfl_xor(s,  off, 64);
    sq += __shfl_xor(sq, off, 64);
  }
  __shared__ float ss[2], sqs[2];
  if(lane == 0){ ss[wid] = s; sqs[wid] = sq; }
  __syncthreads();
  s = ss[0] + ss[1]; sq = sqs[0] + sqs[1];
  float mu  = s * (1.0f / E_);
  float var = sq * (1.0f / E_) - mu * mu;
  float rs  = rsqrtf(var + 1e-6f);
  float4 gv = ((const float4*)g)[tid];
  float4 o = { (v.x-mu)*rs*gv.x, (v.y-mu)*rs*gv.y, (v.z-mu)*rs*gv.z, (v.w-mu)*rs*gv.w };
  ((float4*)(out + (long long)row * E_))[tid] = o;
}

// ---------------- generic MFMA GEMM: C = act(A@W + bias) (+res) ------------
__global__ __launch_bounds__(256) void gemm_k(const float* __restrict__ A,
                                              const float* __restrict__ W,
                                              const float* __restrict__ bias,
                                              const float* __restrict__ res,
                                              float* __restrict__ C,
                                              int M, int N, int K, int act){
  __shared__ short As[64][40];   // [m][k], pad 32->40 (16B-aligned rows)
  __shared__ short Bs[64][40];   // [n][k] (transposed weight tile)
  int tid  = threadIdx.x;
  long long m0 = (long long)blockIdx.y * 64;
  long long n0 = (long long)blockIdx.x * 64;
  int wave = tid >> 6, lane = tid & 63, quad = lane >> 4, l16 = lane & 15;
  floatx4 acc[4] = {{0,0,0,0},{0,0,0,0},{0,0,0,0},{0,0,0,0}};

  int ar = tid >> 2,  ac  = (tid & 3) * 8;   // A staging: row, col-chunk
  int bk = tid >> 3,  bn8 = (tid & 7) * 8;   // W staging: k-row, n-chunk

  for(int k0 = 0; k0 < K; k0 += 32){
    const float* ap = A + (m0 + ar) * K + k0 + ac;
    float4 a0 = ((const float4*)ap)[0], a1 = ((const float4*)ap)[1];
    shortx8 av;
    av[0]=f2bf(a0.x); av[1]=f2bf(a0.y); av[2]=f2bf(a0.z); av[3]=f2bf(a0.w);
    av[4]=f2bf(a1.x); av[5]=f2bf(a1.y); av[6]=f2bf(a1.z); av[7]=f2bf(a1.w);
    *((shortx8*)&As[ar][ac]) = av;

    const float* bp = W + (long long)(k0 + bk) * N + n0 + bn8;
    float4 b0 = ((const float4*)bp)[0], b1 = ((const float4*)bp)[1];
    Bs[bn8+0][bk]=f2bf(b0.x); Bs[bn8+1][bk]=f2bf(b0.y);
    Bs[bn8+2][bk]=f2bf(b0.z); Bs[bn8+3][bk]=f2bf(b0.w);
    Bs[bn8+4][bk]=f2bf(b1.x); Bs[bn8+5][bk]=f2bf(b1.y);
    Bs[bn8+6][bk]=f2bf(b1.z); Bs[bn8+7][bk]=f2bf(b1.w);
    __syncthreads();

    shortx8 af = *((const shortx8*)&As[16*wave + l16][quad*8]);
    #pragma unroll
    for(int t = 0; t < 4; t++){
      shortx8 bf8 = *((const shortx8*)&Bs[16*t + l16][quad*8]);
      acc[t] = __builtin_amdgcn_mfma_f32_16x16x32_bf16(af, bf8, acc[t], 0, 0, 0);
    }
    __syncthreads();
  }

  #pragma unroll
  for(int t = 0; t < 4; t++){
    #pragma unroll
    for(int r = 0; r < 4; r++){
      long long row = m0 + 16*wave + quad*4 + r;
      long long col = n0 + 16*t + l16;
      float v = acc[t][r];
      if(bias) v += bias[col];
      if(act)  v = gelu_exact(v);
      if(res)  v += res[row * N + col];
      C[row * N + col] = v;
    }
  }
}

// ---------------- flash attention, MFMA 16x16x32 bf16 ----------------------
// One block = one (b,h) x 64-row Q tile. 4 waves, each owns 16 q-rows.
// Swapped-operand QK^T: s[t] = mfma(K_frag, Q_frag) -> lane (quad,l16) holds
// scores for q-row (q0+16w+l16) at k = k0+16t+quad*4+r  => row-reduce is
// in-lane + 2 shfl_xor, and P packs as 4x ds_write_b64.
__global__ __launch_bounds__(256) void fattn_k(const float* __restrict__ qkv,
                                               float* __restrict__ out){
  __shared__ short Ks[64*64];      // K tile,  [k][d] bf16, swizzled   8KB
  __shared__ short Vt[64*64];      // V tile,  [d][k] bf16, swizzled   8KB
  __shared__ short Ps[4*16*64];    // per-wave P, [q16][k64] bf16      8KB
  int tid = threadIdx.x, wave = tid >> 6, lane = tid & 63;
  int quad = lane >> 4, l16 = lane & 15;
  int bh = blockIdx.x & 15;
  int qt = 31 - (blockIdx.x >> 4);   // heavy q-tiles dispatch first
  int b = bh >> 3, h = bh & 7;
  int q0 = qt * 64;

  const float* base = qkv + (long long)b * S_ * (3*E_);
  const float* Qb = base + h*64;
  const float* Kb = base + E_   + h*64;
  const float* Vb = base + 2*E_ + h*64;

  // Q fragments (B-operand): lane needs Q[q0+16w+l16][quad*8+32ks .. +8]
  // pre-scaled by 1/sqrt(64)=0.125 (power of two -> exact in bf16)
  shortx8 qf[2];
  {
    const float* qp = Qb + (long long)(q0 + 16*wave + l16) * (3*E_) + quad*8;
    #pragma unroll
    for(int ks2 = 0; ks2 < 2; ks2++){
      float4 a0 = ((const float4*)(qp + 32*ks2))[0];
      float4 a1 = ((const float4*)(qp + 32*ks2))[1];
      shortx8 v;
      v[0]=f2bf(a0.x*0.125f); v[1]=f2bf(a0.y*0.125f);
      v[2]=f2bf(a0.z*0.125f); v[3]=f2bf(a0.w*0.125f);
      v[4]=f2bf(a1.x*0.125f); v[5]=f2bf(a1.y*0.125f);
      v[6]=f2bf(a1.z*0.125f); v[7]=f2bf(a1.w*0.125f);
      qf[ks2] = v;
    }
  }

  float m_s = -1e30f, l_s = 0.f;     // online softmax state for q = q0+16w+l16
  floatx4 acc_o[4] = {{0,0,0,0},{0,0,0,0},{0,0,0,0},{0,0,0,0}};

  int kk  = tid >> 2,        dd  = (tid & 3) * 16;  // K staging: row, 16-col chunk
  int vk4 = (tid >> 4) * 4,  vd4 = (tid & 15) * 4;  // V staging: 4 rows, 4 cols
  char* pbase = (char*)Ps + wave * 2048;

  for(int k0 = 0; k0 <= q0; k0 += 64){
    { // ---- stage K tile (coalesced float4 reads, bf16 b128 writes) ----
      const float* kp = Kb + (long long)(k0 + kk) * (3*E_) + dd;
      float4 x0 = ((const float4*)kp)[0], x1 = ((const float4*)kp)[1];
      float4 x2 = ((const float4*)kp)[2], x3 = ((const float4*)kp)[3];
      shortx8 w0, w1;
      w0[0]=f2bf(x0.x); w0[1]=f2bf(x0.y); w0[2]=f2bf(x0.z); w0[3]=f2bf(x0.w);
      w0[4]=f2bf(x1.x); w0[5]=f2bf(x1.y); w0[6]=f2bf(x1.z); w0[7]=f2bf(x1.w);
      w1[0]=f2bf(x2.x); w1[1]=f2bf(x2.y); w1[2]=f2bf(x2.z); w1[3]=f2bf(x2.w);
      w1[4]=f2bf(x3.x); w1[5]=f2bf(x3.y); w1[6]=f2bf(x3.z); w1[7]=f2bf(x3.w);
      *(shortx8*)lds_at(Ks, kk, dd*2)      = w0;
      *(shortx8*)lds_at(Ks, kk, dd*2 + 16) = w1;
      // ---- stage V transposed: Vt[d][k] (register 4x4 transpose, b64 writes)
      const float* vp = Vb + (long long)(k0 + vk4) * (3*E_) + vd4;
      float4 r0 = ((const float4*)vp)[0];
      float4 r1 = *(const float4*)(vp +     (3*E_));
      float4 r2 = *(const float4*)(vp + 2LL*(3*E_));
      float4 r3 = *(const float4*)(vp + 3LL*(3*E_));
      shortx4 v0 = {f2bf(r0.x), f2bf(r1.x), f2bf(r2.x), f2bf(r3.x)};
      shortx4 v1 = {f2bf(r0.y), f2bf(r1.y), f2bf(r2.y), f2bf(r3.y)};
      shortx4 v2 = {f2bf(r0.z), f2bf(r1.z), f2bf(r2.z), f2bf(r3.z)};
      shortx4 v3 = {f2bf(r0.w), f2bf(r1.w), f2bf(r2.w), f2bf(r3.w)};
      *(shortx4*)lds_at(Vt, vd4+0, vk4*2) = v0;
      *(shortx4*)lds_at(Vt, vd4+1, vk4*2) = v1;
      *(shortx4*)lds_at(Vt, vd4+2, vk4*2) = v2;
      *(shortx4*)lds_at(Vt, vd4+3, vk4*2) = v3;
    }
    __syncthreads();

    // ---- S^T = K @ Q^T : lane holds s[t][r] = score(q=q0+16w+l16, k=k0+16t+quad*4+r)
    floatx4 s[4] = {{0,0,0,0},{0,0,0,0},{0,0,0,0},{0,0,0,0}};
    #pragma unroll
    for(int ks2 = 0; ks2 < 2; ks2++){
      #pragma unroll
      for(int t = 0; t < 4; t++){
        shortx8 kf = *(const shortx8*)lds_at(Ks, 16*t + l16, quad*16 + ks2*64);
        s[t] = __builtin_amdgcn_mfma_f32_16x16x32_bf16(kf, qf[ks2], s[t], 0, 0, 0);
      }
    }

    if(k0 == q0){ // causal mask — only the diagonal tile is partial
      int q = q0 + 16*wave + l16;
      #pragma unroll
      for(int t = 0; t < 4; t++){
        #pragma unroll
        for(int r = 0; r < 4; r++){
          int k = k0 + 16*t + quad*4 + r;
          if(k > q) s[t][r] = -1e30f;
        }
      }
    }

    // ---- online softmax (row = this lane's q; cols spread over 4 quads) ----
    float mloc = -1e30f;
    #pragma unroll
    for(int t = 0; t < 4; t++)
      mloc = fmaxf(mloc, fmaxf(fmaxf(s[t][0], s[t][1]), fmaxf(s[t][2], s[t][3])));
    mloc = fmaxf(mloc, __shfl_xor(mloc, 16, 64));
    mloc = fmaxf(mloc, __shfl_xor(mloc, 32, 64));
    float mnew  = fmaxf(m_s, mloc);
    float scale = __expf(m_s - mnew);        // m_s=-1e30 first iter -> 0
    float sumloc = 0.f;
    shortx4 pw[4];
    #pragma unroll
    for(int t = 0; t < 4; t++){
      #pragma unroll
      for(int r = 0; r < 4; r++){
        float e = __expf(s[t][r] - mnew);
        short pb = f2bf(e);
        pw[t][r] = pb;
        sumloc += bf2f(pb);                  // denom from bf16-rounded P: no bias
      }
    }
    sumloc += __shfl_xor(sumloc, 16, 64);
    sumloc += __shfl_xor(sumloc, 32, 64);
    l_s = l_s * scale + sumloc;
    m_s = mnew;

    // ---- P -> LDS (row l16, 4 consecutive k per write) ----
    #pragma unroll
    for(int t = 0; t < 4; t++)
      *(shortx4*)lds_at(pbase, l16, 32*t + 8*quad) = pw[t];
    asm volatile("" ::: "memory");   // pin P writes before same-wave P reads

    // ---- rescale O (row quad*4+r state lives at l16 == quad*4+r) ----
    #pragma unroll
    for(int r = 0; r < 4; r++){
      float sc = __shfl(scale, (lane & 48) | (quad*4 + r), 64);
      #pragma unroll
      for(int t = 0; t < 4; t++) acc_o[t][r] *= sc;
    }

    // ---- O += P @ V ----
    #pragma unroll
    for(int ks2 = 0; ks2 < 2; ks2++){
      shortx8 pf = *(const shortx8*)lds_at(pbase, l16, quad*16 + ks2*64);
      #pragma unroll
      for(int t = 0; t < 4; t++){
        shortx8 vf = *(const shortx8*)lds_at(Vt, 16*t + l16, quad*16 + ks2*64);
        acc_o[t] = __builtin_amdgcn_mfma_f32_16x16x32_bf16(pf, vf, acc_o[t], 0, 0, 0);
      }
    }
    __syncthreads();
  }

  // ---- normalize + store: O row = q0+16w+quad*4+r, col d = 16t+l16 ----
  #pragma unroll
  for(int r = 0; r < 4; r++){
    float li  = __shfl(l_s, (lane & 48) | (quad*4 + r), 64);
    float inv = 1.0f / li;
    int qrow = q0 + 16*wave + quad*4 + r;
    float* op = out + ((long long)(b*S_ + qrow)) * E_ + h*64 + l16;
    #pragma unroll
    for(int t = 0; t < 4; t++) op[16*t] = acc_o[t][r] * inv;
  }
}

// ---------------------------------------------------------------------------
extern "C" void kernel_launch(void* const* d_in, const int* in_sizes, int n_in,
                              void* d_out, int out_size, void* d_ws, size_t ws_size,
                              hipStream_t stream){
  const int*   ids    = (const int*)d_in[0];
  const float* tok    = (const float*)d_in[1];
  const float* pos    = (const float*)d_in[2];
  const float* qkv_w  = (const float*)d_in[3];
  const float* qkv_b  = (const float*)d_in[4];
  const float* proj_w = (const float*)d_in[5];
  const float* proj_b = (const float*)d_in[6];
  const float* fc1_w  = (const float*)d_in[7];
  const float* fc1_b  = (const float*)d_in[8];
  const float* fc2_w  = (const float*)d_in[9];
  const float* fc2_b  = (const float*)d_in[10];
  const float* ln1_g  = (const float*)d_in[11];
  const float* ln2_g  = (const float*)d_in[12];
  const float* lnf_g  = (const float*)d_in[13];
  const float* out_w  = (const float*)d_in[14];
  float* logits = (float*)d_out;

  char* w = (char*)d_ws;
  float* x   = (float*)(w);                        // [4096,512]   8 MB
  float* h   = (float*)(w + (8ll  << 20));         // [4096,512]   8 MB
  float* qkv = (float*)(w + (16ll << 20));         // [4096,1536] 24 MB
  float* f1  = (float*)(w + (40ll << 20));         // [4096,2048] 32 MB

  embed_k<<<M_, 128, 0, stream>>>(ids, tok, pos, x);

  for(int l = 0; l < L_; l++){
    ln_k<<<M_, 128, 0, stream>>>(x, ln1_g + l*E_, h);
    gemm_k<<<dim3(1536/64, M_/64), 256, 0, stream>>>(
        h, qkv_w + (long long)l*E_*1536, qkv_b + l*1536, nullptr, qkv,
        M_, 1536, E_, 0);
    fattn_k<<<(B_*H_) * (S_/64), 256, 0, stream>>>(qkv, h);
    gemm_k<<<dim3(512/64, M_/64), 256, 0, stream>>>(
        h, proj_w + (long long)l*E_*E_, proj_b + l*E_, x, x,
        M_, E_, E_, 0);
    ln_k<<<M_, 128, 0, stream>>>(x, ln2_g + l*E_, h);
    gemm_k<<<dim3(2048/64, M_/64), 256, 0, stream>>>(
        h, fc1_w + (long long)l*E_*2048, fc1_b + l*2048, nullptr, f1,
        M_, 2048, E_, 1);
    gemm_k<<<dim3(512/64, M_/64), 256, 0, stream>>>(
        f1, fc2_w + (long long)l*2048*E_, fc2_b + l*E_, x, x,
        M_, E_, 2048, 0);
  }

  ln_k<<<M_, 128, 0, stream>>>(x, lnf_g, h);
  gemm_k<<<dim3(V_/64, M_/64), 256, 0, stream>>>(
      h, out_w, nullptr, nullptr, logits,
      M_, V_, E_, 0);
}

// Round 2
// 2450.938 us; speedup vs baseline: 4.5380x; 1.2500x over previous
//
#include <hip/hip_runtime.h>
#include <math.h>

#define L_ 6
#define H_ 8
#define D_HD 64
#define E_ 512
#define V_ 32000
#define S_ 2048
#define B_ 2
#define M_ (B_*S_)   // 4096 rows

typedef float  floatx4 __attribute__((ext_vector_type(4)));
typedef short  shortx8 __attribute__((ext_vector_type(8)));
typedef short  shortx4 __attribute__((ext_vector_type(4)));

__device__ __forceinline__ short f2bf(float f){
  unsigned u = __builtin_bit_cast(unsigned, f);
  u += 0x7FFFu + ((u >> 16) & 1u);   // round-to-nearest-even
  return (short)(u >> 16);
}
__device__ __forceinline__ float bf2f(short s){
  unsigned u = ((unsigned)(unsigned short)s) << 16;
  return __builtin_bit_cast(float, u);
}
__device__ __forceinline__ float gelu_exact(float x){
  return 0.5f * x * (1.0f + erff(x * 0.70710678118654752440f));
}

typedef const __attribute__((address_space(1))) unsigned int* gas_p;
typedef __attribute__((address_space(3))) unsigned int* las_p;
__device__ __forceinline__ void gl16(const void* g, void* l){
  __builtin_amdgcn_global_load_lds((gas_p)g, (las_p)l, 16, 0, 0);
}

// XOR bank swizzle for 128B-row LDS tiles (attention K/V/P tiles)
__device__ __forceinline__ char* lds_at(void* base, int row, int colByte){
  return (char*)base + (((row << 7) + colByte) ^ ((row & 7) << 4));
}

// ---------------- embedding: x = tok_emb[id]/sqrt(E) + pos_emb[s] ----------
__global__ __launch_bounds__(128) void embed_k(const int* __restrict__ ids,
                                               const float* __restrict__ tok,
                                               const float* __restrict__ pos,
                                               float* __restrict__ x){
  int row = blockIdx.x;
  int s   = row & (S_ - 1);
  int id  = ids[row];
  const float4* te = (const float4*)(tok + (long long)id * E_);
  const float4* pe = (const float4*)(pos + (long long)s  * E_);
  float4 a = te[threadIdx.x];
  float4 b = pe[threadIdx.x];
  const float isq = 0.04419417382415922f;  // 1/sqrt(512)
  float4 o = { a.x*isq + b.x, a.y*isq + b.y, a.z*isq + b.z, a.w*isq + b.w };
  ((float4*)(x + (long long)row * E_))[threadIdx.x] = o;
}

// ---------------- LayerNorm, bf16 output (rounding point == old staging) ---
__global__ __launch_bounds__(128) void ln_k(const float* __restrict__ x,
                                            const float* __restrict__ g,
                                            short* __restrict__ out){
  int row = blockIdx.x, tid = threadIdx.x;
  int lane = tid & 63, wid = tid >> 6;
  float4 v = ((const float4*)(x + (long long)row * E_))[tid];
  float s  = v.x + v.y + v.z + v.w;
  float sq = v.x*v.x + v.y*v.y + v.z*v.z + v.w*v.w;
  #pragma unroll
  for(int off = 32; off > 0; off >>= 1){
    s  += __shfl_xor(s,  off, 64);
    sq += __shfl_xor(sq, off, 64);
  }
  __shared__ float ss[2], sqs[2];
  if(lane == 0){ ss[wid] = s; sqs[wid] = sq; }
  __syncthreads();
  s = ss[0] + ss[1]; sq = sqs[0] + sqs[1];
  float mu  = s * (1.0f / E_);
  float var = sq * (1.0f / E_) - mu * mu;
  float rs  = rsqrtf(var + 1e-6f);
  float4 gv = ((const float4*)g)[tid];
  shortx4 ob = { f2bf((v.x-mu)*rs*gv.x), f2bf((v.y-mu)*rs*gv.y),
                 f2bf((v.z-mu)*rs*gv.z), f2bf((v.w-mu)*rs*gv.w) };
  ((shortx4*)(out + (long long)row * E_))[tid] = ob;
}

// ---------------- weight transpose+convert: Wt[n][k] = bf16(W[k][n]) -------
// 64x64 tiles via LDS; blockIdx.z = layer (strides K*N both sides).
__global__ __launch_bounds__(256) void transpose_k(const float* __restrict__ W,
                                                   short* __restrict__ Wt,
                                                   int K, int N){
  __shared__ short t[64][68];
  int tid = threadIdx.x;
  int r16 = tid >> 4, c4 = (tid & 15) * 4;
  long long base = (long long)blockIdx.z * K * N;
  int n0 = blockIdx.x * 64, k0 = blockIdx.y * 64;
  #pragma unroll
  for(int ph = 0; ph < 4; ph++){
    int row = ph*16 + r16;
    float4 v = *(const float4*)(W + base + (long long)(k0+row)*N + n0 + c4);
    t[row][c4+0]=f2bf(v.x); t[row][c4+1]=f2bf(v.y);
    t[row][c4+2]=f2bf(v.z); t[row][c4+3]=f2bf(v.w);
  }
  __syncthreads();
  #pragma unroll
  for(int ph = 0; ph < 4; ph++){
    int orow = ph*16 + r16;   // n-local
    shortx4 o = { t[c4+0][orow], t[c4+1][orow], t[c4+2][orow], t[c4+3][orow] };
    *(shortx4*)(Wt + base + (long long)(n0+orow)*K + k0 + c4) = o;
  }
}

// ---------------- MFMA GEMM, bf16 A x bf16 Wt^T, 128x128 tile, BK=32 -------
// A:[M,K] bf16, Wt:[N,K] bf16. global_load_lds staging (linear LDS dest),
// XOR-swizzled layout via pre-swizzled global source (rule #21):
//   lds slot(row, q) = q ^ (row&3) ^ ((row>>2)&3)  -> <=2-way on ds_read_b128.
// Block order: m-tile fastest (W panel stays L2-hot) + bijective XCD swizzle.
__global__ __launch_bounds__(256) void gemm_bf_k(const short* __restrict__ A,
                                                 const short* __restrict__ Wt,
                                                 const float* __restrict__ bias,
                                                 const float* __restrict__ res,
                                                 void* __restrict__ Cout,
                                                 int M, int N, int K,
                                                 int act, int outbf){
  __shared__ short As[4096];   // [128][32] bf16, swizzled   8 KB
  __shared__ short Bs[4096];   // [128][32] bf16, swizzled   8 KB
  int tid = threadIdx.x;
  int wave = tid >> 6, lane = tid & 63, quad = lane >> 4, l16 = lane & 15;
  int wr = wave >> 1, wc = wave & 1;

  int MT  = M >> 7;
  int nwg = gridDim.x, bid = blockIdx.x;
  int nb  = bid;
  if((nwg & 7) == 0) nb = (bid & 7) * (nwg >> 3) + (bid >> 3);
  long long m0 = (long long)(nb % MT) << 7;
  long long n0 = (long long)(nb / MT) << 7;

  // staging: lds byte tid*16 (+4096 for issue 1) <-> row=tid>>2, slot=tid&3;
  // source chunk gq = slot ^ f(row), f(row)=(row&3)^((row>>2)&3) (issue-invariant)
  int rs = tid >> 2;
  int gq = (tid & 3) ^ ((tid >> 2) & 3) ^ ((tid >> 4) & 3);
  const short* a0 = A  + (m0 + rs)      * (long long)K + gq * 8;
  const short* a1 = A  + (m0 + rs + 64) * (long long)K + gq * 8;
  const short* b0 = Wt + (n0 + rs)      * (long long)K + gq * 8;
  const short* b1 = Wt + (n0 + rs + 64) * (long long)K + gq * 8;
  char* dA = (char*)As + wave * 1024;
  char* dB = (char*)Bs + wave * 1024;

  int aoff[4], boff[4];
  #pragma unroll
  for(int t = 0; t < 4; t++){
    int ra = wr*64 + t*16 + l16;
    aoff[t] = ra*64 + ((quad ^ (ra & 3) ^ ((ra >> 2) & 3)) << 4);
    int rb = wc*64 + t*16 + l16;
    boff[t] = rb*64 + ((quad ^ (rb & 3) ^ ((rb >> 2) & 3)) << 4);
  }

  floatx4 acc[4][4];
  #pragma unroll
  for(int i = 0; i < 4; i++)
    #pragma unroll
    for(int j = 0; j < 4; j++)
      acc[i][j] = (floatx4){0.f, 0.f, 0.f, 0.f};

  for(int k0 = 0; k0 < K; k0 += 32){
    gl16(a0, dA);        gl16(a1, dA + 4096);
    gl16(b0, dB);        gl16(b1, dB + 4096);
    a0 += 32; a1 += 32; b0 += 32; b1 += 32;
    __syncthreads();
    shortx8 af[4], bfr[4];
    #pragma unroll
    for(int t = 0; t < 4; t++){
      af[t]  = *(const shortx8*)((const char*)As + aoff[t]);
      bfr[t] = *(const shortx8*)((const char*)Bs + boff[t]);
    }
    #pragma unroll
    for(int i = 0; i < 4; i++)
      #pragma unroll
      for(int j = 0; j < 4; j++)
        acc[i][j] = __builtin_amdgcn_mfma_f32_16x16x32_bf16(af[i], bfr[j], acc[i][j], 0, 0, 0);
    __syncthreads();
  }

  #pragma unroll
  for(int i = 0; i < 4; i++){
    #pragma unroll
    for(int r = 0; r < 4; r++){
      long long row = m0 + wr*64 + i*16 + quad*4 + r;
      #pragma unroll
      for(int j = 0; j < 4; j++){
        long long col = n0 + wc*64 + j*16 + l16;
        float v = acc[i][j][r];
        if(bias) v += bias[col];
        if(act)  v = gelu_exact(v);
        if(res)  v += res[row * N + col];
        if(outbf) ((short*)Cout)[row * N + col] = f2bf(v);
        else      ((float*)Cout)[row * N + col] = v;
      }
    }
  }
}

// ---------------- flash attention, MFMA 16x16x32 bf16, bf16 output ---------
__global__ __launch_bounds__(256) void fattn_k(const float* __restrict__ qkv,
                                               short* __restrict__ out){
  __shared__ short Ks[64*64];      // K tile,  [k][d] bf16, swizzled   8KB
  __shared__ short Vt[64*64];      // V tile,  [d][k] bf16, swizzled   8KB
  __shared__ short Ps[4*16*64];    // per-wave P, [q16][k64] bf16      8KB
  int tid = threadIdx.x, wave = tid >> 6, lane = tid & 63;
  int quad = lane >> 4, l16 = lane & 15;
  int bh = blockIdx.x & 15;
  int qt = 31 - (blockIdx.x >> 4);   // heavy q-tiles dispatch first
  int b = bh >> 3, h = bh & 7;
  int q0 = qt * 64;

  const float* base = qkv + (long long)b * S_ * (3*E_);
  const float* Qb = base + h*64;
  const float* Kb = base + E_   + h*64;
  const float* Vb = base + 2*E_ + h*64;

  shortx8 qf[2];
  {
    const float* qp = Qb + (long long)(q0 + 16*wave + l16) * (3*E_) + quad*8;
    #pragma unroll
    for(int ks2 = 0; ks2 < 2; ks2++){
      float4 a0 = ((const float4*)(qp + 32*ks2))[0];
      float4 a1 = ((const float4*)(qp + 32*ks2))[1];
      shortx8 v;
      v[0]=f2bf(a0.x*0.125f); v[1]=f2bf(a0.y*0.125f);
      v[2]=f2bf(a0.z*0.125f); v[3]=f2bf(a0.w*0.125f);
      v[4]=f2bf(a1.x*0.125f); v[5]=f2bf(a1.y*0.125f);
      v[6]=f2bf(a1.z*0.125f); v[7]=f2bf(a1.w*0.125f);
      qf[ks2] = v;
    }
  }

  float m_s = -1e30f, l_s = 0.f;
  floatx4 acc_o[4] = {{0,0,0,0},{0,0,0,0},{0,0,0,0},{0,0,0,0}};

  int kk  = tid >> 2,        dd  = (tid & 3) * 16;
  int vk4 = (tid >> 4) * 4,  vd4 = (tid & 15) * 4;
  char* pbase = (char*)Ps + wave * 2048;

  for(int k0 = 0; k0 <= q0; k0 += 64){
    {
      const float* kp = Kb + (long long)(k0 + kk) * (3*E_) + dd;
      float4 x0 = ((const float4*)kp)[0], x1 = ((const float4*)kp)[1];
      float4 x2 = ((const float4*)kp)[2], x3 = ((const float4*)kp)[3];
      shortx8 w0, w1;
      w0[0]=f2bf(x0.x); w0[1]=f2bf(x0.y); w0[2]=f2bf(x0.z); w0[3]=f2bf(x0.w);
      w0[4]=f2bf(x1.x); w0[5]=f2bf(x1.y); w0[6]=f2bf(x1.z); w0[7]=f2bf(x1.w);
      w1[0]=f2bf(x2.x); w1[1]=f2bf(x2.y); w1[2]=f2bf(x2.z); w1[3]=f2bf(x2.w);
      w1[4]=f2bf(x3.x); w1[5]=f2bf(x3.y); w1[6]=f2bf(x3.z); w1[7]=f2bf(x3.w);
      *(shortx8*)lds_at(Ks, kk, dd*2)      = w0;
      *(shortx8*)lds_at(Ks, kk, dd*2 + 16) = w1;
      const float* vp = Vb + (long long)(k0 + vk4) * (3*E_) + vd4;
      float4 r0 = ((const float4*)vp)[0];
      float4 r1 = *(const float4*)(vp +     (3*E_));
      float4 r2 = *(const float4*)(vp + 2LL*(3*E_));
      float4 r3 = *(const float4*)(vp + 3LL*(3*E_));
      shortx4 v0 = {f2bf(r0.x), f2bf(r1.x), f2bf(r2.x), f2bf(r3.x)};
      shortx4 v1 = {f2bf(r0.y), f2bf(r1.y), f2bf(r2.y), f2bf(r3.y)};
      shortx4 v2 = {f2bf(r0.z), f2bf(r1.z), f2bf(r2.z), f2bf(r3.z)};
      shortx4 v3 = {f2bf(r0.w), f2bf(r1.w), f2bf(r2.w), f2bf(r3.w)};
      *(shortx4*)lds_at(Vt, vd4+0, vk4*2) = v0;
      *(shortx4*)lds_at(Vt, vd4+1, vk4*2) = v1;
      *(shortx4*)lds_at(Vt, vd4+2, vk4*2) = v2;
      *(shortx4*)lds_at(Vt, vd4+3, vk4*2) = v3;
    }
    __syncthreads();

    floatx4 s[4] = {{0,0,0,0},{0,0,0,0},{0,0,0,0},{0,0,0,0}};
    #pragma unroll
    for(int ks2 = 0; ks2 < 2; ks2++){
      #pragma unroll
      for(int t = 0; t < 4; t++){
        shortx8 kf = *(const shortx8*)lds_at(Ks, 16*t + l16, quad*16 + ks2*64);
        s[t] = __builtin_amdgcn_mfma_f32_16x16x32_bf16(kf, qf[ks2], s[t], 0, 0, 0);
      }
    }

    if(k0 == q0){
      int q = q0 + 16*wave + l16;
      #pragma unroll
      for(int t = 0; t < 4; t++){
        #pragma unroll
        for(int r = 0; r < 4; r++){
          int k = k0 + 16*t + quad*4 + r;
          if(k > q) s[t][r] = -1e30f;
        }
      }
    }

    float mloc = -1e30f;
    #pragma unroll
    for(int t = 0; t < 4; t++)
      mloc = fmaxf(mloc, fmaxf(fmaxf(s[t][0], s[t][1]), fmaxf(s[t][2], s[t][3])));
    mloc = fmaxf(mloc, __shfl_xor(mloc, 16, 64));
    mloc = fmaxf(mloc, __shfl_xor(mloc, 32, 64));
    float mnew  = fmaxf(m_s, mloc);
    float scale = __expf(m_s - mnew);
    float sumloc = 0.f;
    shortx4 pw[4];
    #pragma unroll
    for(int t = 0; t < 4; t++){
      #pragma unroll
      for(int r = 0; r < 4; r++){
        float e = __expf(s[t][r] - mnew);
        short pb = f2bf(e);
        pw[t][r] = pb;
        sumloc += bf2f(pb);
      }
    }
    sumloc += __shfl_xor(sumloc, 16, 64);
    sumloc += __shfl_xor(sumloc, 32, 64);
    l_s = l_s * scale + sumloc;
    m_s = mnew;

    #pragma unroll
    for(int t = 0; t < 4; t++)
      *(shortx4*)lds_at(pbase, l16, 32*t + 8*quad) = pw[t];
    asm volatile("" ::: "memory");

    #pragma unroll
    for(int r = 0; r < 4; r++){
      float sc = __shfl(scale, (lane & 48) | (quad*4 + r), 64);
      #pragma unroll
      for(int t = 0; t < 4; t++) acc_o[t][r] *= sc;
    }

    #pragma unroll
    for(int ks2 = 0; ks2 < 2; ks2++){
      shortx8 pf = *(const shortx8*)lds_at(pbase, l16, quad*16 + ks2*64);
      #pragma unroll
      for(int t = 0; t < 4; t++){
        shortx8 vf = *(const shortx8*)lds_at(Vt, 16*t + l16, quad*16 + ks2*64);
        acc_o[t] = __builtin_amdgcn_mfma_f32_16x16x32_bf16(pf, vf, acc_o[t], 0, 0, 0);
      }
    }
    __syncthreads();
  }

  #pragma unroll
  for(int r = 0; r < 4; r++){
    float li  = __shfl(l_s, (lane & 48) | (quad*4 + r), 64);
    float inv = 1.0f / li;
    int qrow = q0 + 16*wave + quad*4 + r;
    short* op = out + ((long long)(b*S_ + qrow)) * E_ + h*64 + l16;
    #pragma unroll
    for(int t = 0; t < 4; t++) op[16*t] = f2bf(acc_o[t][r] * inv);
  }
}

// ---------------------------------------------------------------------------
extern "C" void kernel_launch(void* const* d_in, const int* in_sizes, int n_in,
                              void* d_out, int out_size, void* d_ws, size_t ws_size,
                              hipStream_t stream){
  const int*   ids    = (const int*)d_in[0];
  const float* tok    = (const float*)d_in[1];
  const float* pos    = (const float*)d_in[2];
  const float* qkv_w  = (const float*)d_in[3];
  const float* qkv_b  = (const float*)d_in[4];
  const float* proj_w = (const float*)d_in[5];
  const float* proj_b = (const float*)d_in[6];
  const float* fc1_w  = (const float*)d_in[7];
  const float* fc1_b  = (const float*)d_in[8];
  const float* fc2_w  = (const float*)d_in[9];
  const float* fc2_b  = (const float*)d_in[10];
  const float* ln1_g  = (const float*)d_in[11];
  const float* ln2_g  = (const float*)d_in[12];
  const float* lnf_g  = (const float*)d_in[13];
  const float* out_w  = (const float*)d_in[14];
  float* logits = (float*)d_out;

  char* w = (char*)d_ws;
  float* x    = (float*)(w);                       // [4096,512]  fp32   8 MB
  short* h    = (short*)(w + (8ll  << 20));        // [4096,512]  bf16   4 MB
  float* qkv  = (float*)(w + (12ll << 20));        // [4096,1536] fp32  24 MB
  short* f1   = (short*)(w + (36ll << 20));        // [4096,2048] bf16  16 MB
  short* wpool= (short*)(w + (52ll << 20));        // bf16 Wt pool    70.6 MB
  short* qkvT = wpool;                             // [6][1536][512]
  short* projT= qkvT + 6ll*1536*512;               // [6][512][512]
  short* fc1T = projT + 6ll*512*512;               // [6][2048][512]
  short* fc2T = fc1T + 6ll*2048*512;               // [6][512][2048]
  short* outT = fc2T + 6ll*512*2048;               // [32000][512]

  // one-time weight convert+transpose (Wt[n][k] = bf16(W[k][n]))
  transpose_k<<<dim3(1536/64, 512/64, L_), 256, 0, stream>>>(qkv_w,  qkvT, 512, 1536);
  transpose_k<<<dim3( 512/64, 512/64, L_), 256, 0, stream>>>(proj_w, projT, 512, 512);
  transpose_k<<<dim3(2048/64, 512/64, L_), 256, 0, stream>>>(fc1_w,  fc1T, 512, 2048);
  transpose_k<<<dim3( 512/64,2048/64, L_), 256, 0, stream>>>(fc2_w,  fc2T, 2048, 512);
  transpose_k<<<dim3(V_/64,   512/64, 1 ), 256, 0, stream>>>(out_w,  outT, 512, V_);

  embed_k<<<M_, 128, 0, stream>>>(ids, tok, pos, x);

  for(int l = 0; l < L_; l++){
    ln_k<<<M_, 128, 0, stream>>>(x, ln1_g + l*E_, h);
    gemm_bf_k<<<(M_/128)*(1536/128), 256, 0, stream>>>(
        h, qkvT + (long long)l*1536*512, qkv_b + l*1536, nullptr, qkv,
        M_, 1536, E_, 0, 0);
    fattn_k<<<(B_*H_) * (S_/64), 256, 0, stream>>>(qkv, h);
    gemm_bf_k<<<(M_/128)*(512/128), 256, 0, stream>>>(
        h, projT + (long long)l*512*512, proj_b + l*E_, x, x,
        M_, E_, E_, 0, 0);
    ln_k<<<M_, 128, 0, stream>>>(x, ln2_g + l*E_, h);
    gemm_bf_k<<<(M_/128)*(2048/128), 256, 0, stream>>>(
        h, fc1T + (long long)l*2048*512, fc1_b + l*2048, nullptr, f1,
        M_, 2048, E_, 1, 1);
    gemm_bf_k<<<(M_/128)*(512/128), 256, 0, stream>>>(
        f1, fc2T + (long long)l*512*2048, fc2_b + l*E_, x, x,
        M_, E_, 2048, 0, 0);
  }

  ln_k<<<M_, 128, 0, stream>>>(x, lnf_g, h);
  gemm_bf_k<<<(M_/128)*(V_/128), 256, 0, stream>>>(
      h, outT, nullptr, nullptr, logits,
      M_, V_, E_, 0, 0);
}

// Round 3
// 2090.410 us; speedup vs baseline: 5.3206x; 1.1725x over previous
//
#include <hip/hip_runtime.h>
#include <math.h>

#define L_ 6
#define H_ 8
#define D_HD 64
#define E_ 512
#define V_ 32000
#define S_ 2048
#define B_ 2
#define M_ (B_*S_)   // 4096 rows

typedef float  floatx4 __attribute__((ext_vector_type(4)));
typedef short  shortx8 __attribute__((ext_vector_type(8)));
typedef short  shortx4 __attribute__((ext_vector_type(4)));

__device__ __forceinline__ short f2bf(float f){
  unsigned u = __builtin_bit_cast(unsigned, f);
  u += 0x7FFFu + ((u >> 16) & 1u);   // round-to-nearest-even
  return (short)(u >> 16);
}
__device__ __forceinline__ float bf2f(short s){
  unsigned u = ((unsigned)(unsigned short)s) << 16;
  return __builtin_bit_cast(float, u);
}
__device__ __forceinline__ float gelu_exact(float x){
  return 0.5f * x * (1.0f + erff(x * 0.70710678118654752440f));
}

typedef const __attribute__((address_space(1))) unsigned int* gas_p;
typedef __attribute__((address_space(3))) unsigned int* las_p;
__device__ __forceinline__ void gl16(const void* g, void* l){
  __builtin_amdgcn_global_load_lds((gas_p)g, (las_p)l, 16, 0, 0);
}

// XOR bank swizzle for 128B-row LDS tiles (attention K/V/P tiles)
__device__ __forceinline__ char* lds_at(void* base, int row, int colByte){
  return (char*)base + (((row << 7) + colByte) ^ ((row & 7) << 4));
}

// ---------------- embedding: x = tok_emb[id]/sqrt(E) + pos_emb[s] ----------
__global__ __launch_bounds__(128) void embed_k(const int* __restrict__ ids,
                                               const float* __restrict__ tok,
                                               const float* __restrict__ pos,
                                               float* __restrict__ x){
  int row = blockIdx.x;
  int s   = row & (S_ - 1);
  int id  = ids[row];
  const float4* te = (const float4*)(tok + (long long)id * E_);
  const float4* pe = (const float4*)(pos + (long long)s  * E_);
  float4 a = te[threadIdx.x];
  float4 b = pe[threadIdx.x];
  const float isq = 0.04419417382415922f;  // 1/sqrt(512)
  float4 o = { a.x*isq + b.x, a.y*isq + b.y, a.z*isq + b.z, a.w*isq + b.w };
  ((float4*)(x + (long long)row * E_))[threadIdx.x] = o;
}

// ---------------- LayerNorm, bf16 output (rounding point == old staging) ---
__global__ __launch_bounds__(128) void ln_k(const float* __restrict__ x,
                                            const float* __restrict__ g,
                                            short* __restrict__ out){
  int row = blockIdx.x, tid = threadIdx.x;
  int lane = tid & 63, wid = tid >> 6;
  float4 v = ((const float4*)(x + (long long)row * E_))[tid];
  float s  = v.x + v.y + v.z + v.w;
  float sq = v.x*v.x + v.y*v.y + v.z*v.z + v.w*v.w;
  #pragma unroll
  for(int off = 32; off > 0; off >>= 1){
    s  += __shfl_xor(s,  off, 64);
    sq += __shfl_xor(sq, off, 64);
  }
  __shared__ float ss[2], sqs[2];
  if(lane == 0){ ss[wid] = s; sqs[wid] = sq; }
  __syncthreads();
  s = ss[0] + ss[1]; sq = sqs[0] + sqs[1];
  float mu  = s * (1.0f / E_);
  float var = sq * (1.0f / E_) - mu * mu;
  float rs  = rsqrtf(var + 1e-6f);
  float4 gv = ((const float4*)g)[tid];
  shortx4 ob = { f2bf((v.x-mu)*rs*gv.x), f2bf((v.y-mu)*rs*gv.y),
                 f2bf((v.z-mu)*rs*gv.z), f2bf((v.w-mu)*rs*gv.w) };
  ((shortx4*)(out + (long long)row * E_))[tid] = ob;
}

// ---------------- weight transpose+convert: Wt[n][k] = bf16(W[k][n]) -------
__global__ __launch_bounds__(256) void transpose_k(const float* __restrict__ W,
                                                   short* __restrict__ Wt,
                                                   int K, int N){
  __shared__ short t[64][68];
  int tid = threadIdx.x;
  int r16 = tid >> 4, c4 = (tid & 15) * 4;
  long long base = (long long)blockIdx.z * K * N;
  int n0 = blockIdx.x * 64, k0 = blockIdx.y * 64;
  #pragma unroll
  for(int ph = 0; ph < 4; ph++){
    int row = ph*16 + r16;
    float4 v = *(const float4*)(W + base + (long long)(k0+row)*N + n0 + c4);
    t[row][c4+0]=f2bf(v.x); t[row][c4+1]=f2bf(v.y);
    t[row][c4+2]=f2bf(v.z); t[row][c4+3]=f2bf(v.w);
  }
  __syncthreads();
  #pragma unroll
  for(int ph = 0; ph < 4; ph++){
    int orow = ph*16 + r16;   // n-local
    shortx4 o = { t[c4+0][orow], t[c4+1][orow], t[c4+2][orow], t[c4+3][orow] };
    *(shortx4*)(Wt + base + (long long)(n0+orow)*K + k0 + c4) = o;
  }
}

// ---------------- MFMA GEMM, bf16 A x bf16 Wt^T, 128xBN tile, BK=32 --------
// BN=128: 4 waves 2x2 (64x64 each); BN=64: 4 waves 2x2 (64x32 each).
template<int BN>
__global__ __launch_bounds__(256) void gemm_bf_k(const short* __restrict__ A,
                                                 const short* __restrict__ Wt,
                                                 const float* __restrict__ bias,
                                                 const float* __restrict__ res,
                                                 void* __restrict__ Cout,
                                                 int M, int N, int K,
                                                 int act, int outbf){
  constexpr int NT = BN / 32;       // n-fragments per wave
  __shared__ short As[4096];        // [128][32] bf16, swizzled
  __shared__ short Bs[BN*32];       // [BN][32]  bf16, swizzled
  int tid = threadIdx.x;
  int wave = tid >> 6, lane = tid & 63, quad = lane >> 4, l16 = lane & 15;
  int wr = wave >> 1, wc = wave & 1;

  int MT  = M >> 7;
  int nwg = gridDim.x, bid = blockIdx.x;
  int nb  = bid;
  if((nwg & 7) == 0) nb = (bid & 7) * (nwg >> 3) + (bid >> 3);
  long long m0 = (long long)(nb % MT) << 7;
  long long n0 = (long long)(nb / MT) * BN;

  // staging: lds byte tid*16 (+4096 for issue 1) <-> row=tid>>2, slot=tid&3;
  // source chunk gq = slot ^ f(row), f(row)=(row&3)^((row>>2)&3)
  int rs = tid >> 2;
  int gq = (tid & 3) ^ ((tid >> 2) & 3) ^ ((tid >> 4) & 3);
  const short* a0 = A  + (m0 + rs)      * (long long)K + gq * 8;
  const short* a1 = A  + (m0 + rs + 64) * (long long)K + gq * 8;
  const short* b0 = Wt + (n0 + rs)      * (long long)K + gq * 8;
  const short* b1 = (BN == 128) ? Wt + (n0 + rs + 64) * (long long)K + gq * 8 : nullptr;
  char* dA = (char*)As + wave * 1024;
  char* dB = (char*)Bs + wave * 1024;

  int aoff[4], boff[NT];
  #pragma unroll
  for(int t = 0; t < 4; t++){
    int ra = wr*64 + t*16 + l16;
    aoff[t] = ra*64 + ((quad ^ (ra & 3) ^ ((ra >> 2) & 3)) << 4);
  }
  #pragma unroll
  for(int t = 0; t < NT; t++){
    int rb = wc*(BN/2) + t*16 + l16;
    boff[t] = rb*64 + ((quad ^ (rb & 3) ^ ((rb >> 2) & 3)) << 4);
  }

  floatx4 acc[4][NT];
  #pragma unroll
  for(int i = 0; i < 4; i++)
    #pragma unroll
    for(int j = 0; j < NT; j++)
      acc[i][j] = (floatx4){0.f, 0.f, 0.f, 0.f};

  for(int k0 = 0; k0 < K; k0 += 32){
    gl16(a0, dA);        gl16(a1, dA + 4096);
    gl16(b0, dB);
    if(BN == 128) gl16(b1, dB + 4096);
    a0 += 32; a1 += 32; b0 += 32;
    if(BN == 128) b1 += 32;
    __syncthreads();
    shortx8 af[4], bfr[NT];
    #pragma unroll
    for(int t = 0; t < 4; t++)
      af[t]  = *(const shortx8*)((const char*)As + aoff[t]);
    #pragma unroll
    for(int t = 0; t < NT; t++)
      bfr[t] = *(const shortx8*)((const char*)Bs + boff[t]);
    #pragma unroll
    for(int i = 0; i < 4; i++)
      #pragma unroll
      for(int j = 0; j < NT; j++)
        acc[i][j] = __builtin_amdgcn_mfma_f32_16x16x32_bf16(af[i], bfr[j], acc[i][j], 0, 0, 0);
    __syncthreads();
  }

  #pragma unroll
  for(int i = 0; i < 4; i++){
    #pragma unroll
    for(int r = 0; r < 4; r++){
      long long row = m0 + wr*64 + i*16 + quad*4 + r;
      #pragma unroll
      for(int j = 0; j < NT; j++){
        long long col = n0 + wc*(BN/2) + j*16 + l16;
        float v = acc[i][j][r];
        if(bias) v += bias[col];
        if(act)  v = gelu_exact(v);
        if(res)  v += res[row * N + col];
        if(outbf) ((short*)Cout)[row * N + col] = f2bf(v);
        else      ((float*)Cout)[row * N + col] = v;
      }
    }
  }
}

// ---------------- flash attention, bf16 qkv input, MFMA 16x16x32 -----------
// One block = one (b,h) x 64-row Q tile; 4 waves. Swapped-operand QK^T.
// K staged via global_load_lds (pre-swizzled per-lane source, rule #21);
// scores scaled by 1/sqrt(64)=0.125 AFTER the fp32 MFMA (exact pow2 commute).
__global__ __launch_bounds__(256) void fattn_k(const short* __restrict__ qkv,
                                               short* __restrict__ out){
  __shared__ short Ks[64*64];      // K tile,  [k][d] bf16, swizzled   8KB
  __shared__ short Vt[64*64];      // V tile,  [d][k] bf16, swizzled   8KB
  __shared__ short Ps[4*16*64];    // per-wave P, [q16][k64] bf16      8KB
  int tid = threadIdx.x, wave = tid >> 6, lane = tid & 63;
  int quad = lane >> 4, l16 = lane & 15;
  int bh = blockIdx.x & 15;
  int qt = 31 - (blockIdx.x >> 4);   // heavy q-tiles dispatch first
  int b = bh >> 3, h = bh & 7;
  int q0 = qt * 64;

  const short* base = qkv + (long long)b * S_ * 1536;
  const short* Qb = base + h*64;
  const short* Kb = base + 512  + h*64;
  const short* Vb = base + 1024 + h*64;

  // Q fragments: raw bf16 (scale folded into S afterwards)
  shortx8 qf[2];
  {
    const short* qp = Qb + (long long)(q0 + 16*wave + l16) * 1536 + quad*8;
    qf[0] = *(const shortx8*)(qp);
    qf[1] = *(const shortx8*)(qp + 32);
  }

  float m_s = -1e30f, l_s = 0.f;
  floatx4 acc_o[4] = {{0,0,0,0},{0,0,0,0},{0,0,0,0},{0,0,0,0}};

  // K staging via gl16: issue i covers rows i*32 + wave*8 + (lane>>3),
  // dest chunk lane&7, source chunk (lane&7)^(row&7)  (row&7 issue-invariant)
  int krow   = wave*8 + (lane >> 3);
  int kchunk = (lane & 7) ^ (krow & 7);
  const short* kA = Kb + (long long)krow * 1536 + kchunk * 8;
  char* dK0 = (char*)Ks + wave * 1024;
  char* dK1 = dK0 + 4096;

  // V staging: 4x4 register transpose from bf16 global
  int vk4 = (tid >> 4) * 4, vd4 = (tid & 15) * 4;
  const short* vp = Vb + (long long)vk4 * 1536 + vd4;
  char* pbase = (char*)Ps + wave * 2048;

  for(int k0 = 0; k0 <= q0; k0 += 64){
    gl16(kA, dK0);
    gl16(kA + 32*1536, dK1);
    {
      shortx4 r0 = *(const shortx4*)(vp);
      shortx4 r1 = *(const shortx4*)(vp + 1536);
      shortx4 r2 = *(const shortx4*)(vp + 2*1536);
      shortx4 r3 = *(const shortx4*)(vp + 3*1536);
      shortx4 v0 = {r0[0], r1[0], r2[0], r3[0]};
      shortx4 v1 = {r0[1], r1[1], r2[1], r3[1]};
      shortx4 v2 = {r0[2], r1[2], r2[2], r3[2]};
      shortx4 v3 = {r0[3], r1[3], r2[3], r3[3]};
      *(shortx4*)lds_at(Vt, vd4+0, vk4*2) = v0;
      *(shortx4*)lds_at(Vt, vd4+1, vk4*2) = v1;
      *(shortx4*)lds_at(Vt, vd4+2, vk4*2) = v2;
      *(shortx4*)lds_at(Vt, vd4+3, vk4*2) = v3;
    }
    kA += 64*1536; vp += 64*1536;
    __syncthreads();

    floatx4 s[4] = {{0,0,0,0},{0,0,0,0},{0,0,0,0},{0,0,0,0}};
    #pragma unroll
    for(int ks2 = 0; ks2 < 2; ks2++){
      #pragma unroll
      for(int t = 0; t < 4; t++){
        shortx8 kf = *(const shortx8*)lds_at(Ks, 16*t + l16, quad*16 + ks2*64);
        s[t] = __builtin_amdgcn_mfma_f32_16x16x32_bf16(kf, qf[ks2], s[t], 0, 0, 0);
      }
    }
    #pragma unroll
    for(int t = 0; t < 4; t++){
      #pragma unroll
      for(int r = 0; r < 4; r++) s[t][r] *= 0.125f;
    }

    if(k0 == q0){
      int q = q0 + 16*wave + l16;
      #pragma unroll
      for(int t = 0; t < 4; t++){
        #pragma unroll
        for(int r = 0; r < 4; r++){
          int k = k0 + 16*t + quad*4 + r;
          if(k > q) s[t][r] = -1e30f;
        }
      }
    }

    float mloc = -1e30f;
    #pragma unroll
    for(int t = 0; t < 4; t++)
      mloc = fmaxf(mloc, fmaxf(fmaxf(s[t][0], s[t][1]), fmaxf(s[t][2], s[t][3])));
    mloc = fmaxf(mloc, __shfl_xor(mloc, 16, 64));
    mloc = fmaxf(mloc, __shfl_xor(mloc, 32, 64));
    float mnew  = fmaxf(m_s, mloc);
    float scale = __expf(m_s - mnew);
    float sumloc = 0.f;
    shortx4 pw[4];
    #pragma unroll
    for(int t = 0; t < 4; t++){
      #pragma unroll
      for(int r = 0; r < 4; r++){
        float e = __expf(s[t][r] - mnew);
        short pb = f2bf(e);
        pw[t][r] = pb;
        sumloc += bf2f(pb);
      }
    }
    sumloc += __shfl_xor(sumloc, 16, 64);
    sumloc += __shfl_xor(sumloc, 32, 64);
    l_s = l_s * scale + sumloc;
    m_s = mnew;

    #pragma unroll
    for(int t = 0; t < 4; t++)
      *(shortx4*)lds_at(pbase, l16, 32*t + 8*quad) = pw[t];
    asm volatile("" ::: "memory");

    #pragma unroll
    for(int r = 0; r < 4; r++){
      float sc = __shfl(scale, (lane & 48) | (quad*4 + r), 64);
      #pragma unroll
      for(int t = 0; t < 4; t++) acc_o[t][r] *= sc;
    }

    #pragma unroll
    for(int ks2 = 0; ks2 < 2; ks2++){
      shortx8 pf = *(const shortx8*)lds_at(pbase, l16, quad*16 + ks2*64);
      #pragma unroll
      for(int t = 0; t < 4; t++){
        shortx8 vf = *(const shortx8*)lds_at(Vt, 16*t + l16, quad*16 + ks2*64);
        acc_o[t] = __builtin_amdgcn_mfma_f32_16x16x32_bf16(pf, vf, acc_o[t], 0, 0, 0);
      }
    }
    __syncthreads();
  }

  #pragma unroll
  for(int r = 0; r < 4; r++){
    float li  = __shfl(l_s, (lane & 48) | (quad*4 + r), 64);
    float inv = 1.0f / li;
    int qrow = q0 + 16*wave + quad*4 + r;
    short* op = out + ((long long)(b*S_ + qrow)) * E_ + h*64 + l16;
    #pragma unroll
    for(int t = 0; t < 4; t++) op[16*t] = f2bf(acc_o[t][r] * inv);
  }
}

// ---------------------------------------------------------------------------
extern "C" void kernel_launch(void* const* d_in, const int* in_sizes, int n_in,
                              void* d_out, int out_size, void* d_ws, size_t ws_size,
                              hipStream_t stream){
  const int*   ids    = (const int*)d_in[0];
  const float* tok    = (const float*)d_in[1];
  const float* pos    = (const float*)d_in[2];
  const float* qkv_w  = (const float*)d_in[3];
  const float* qkv_b  = (const float*)d_in[4];
  const float* proj_w = (const float*)d_in[5];
  const float* proj_b = (const float*)d_in[6];
  const float* fc1_w  = (const float*)d_in[7];
  const float* fc1_b  = (const float*)d_in[8];
  const float* fc2_w  = (const float*)d_in[9];
  const float* fc2_b  = (const float*)d_in[10];
  const float* ln1_g  = (const float*)d_in[11];
  const float* ln2_g  = (const float*)d_in[12];
  const float* lnf_g  = (const float*)d_in[13];
  const float* out_w  = (const float*)d_in[14];
  float* logits = (float*)d_out;

  char* w = (char*)d_ws;
  float* x    = (float*)(w);                       // [4096,512]  fp32   8 MB
  short* h    = (short*)(w + (8ll  << 20));        // [4096,512]  bf16   4 MB
  short* qkvb = (short*)(w + (12ll << 20));        // [4096,1536] bf16  12 MB
  short* f1   = (short*)(w + (24ll << 20));        // [4096,2048] bf16  16 MB
  short* wpool= (short*)(w + (40ll << 20));        // bf16 Wt pool    70.6 MB
  short* qkvT = wpool;                             // [6][1536][512]
  short* projT= qkvT + 6ll*1536*512;               // [6][512][512]
  short* fc1T = projT + 6ll*512*512;               // [6][2048][512]
  short* fc2T = fc1T + 6ll*2048*512;               // [6][512][2048]
  short* outT = fc2T + 6ll*512*2048;               // [32000][512]

  // one-time weight convert+transpose (Wt[n][k] = bf16(W[k][n]))
  transpose_k<<<dim3(1536/64, 512/64, L_), 256, 0, stream>>>(qkv_w,  qkvT, 512, 1536);
  transpose_k<<<dim3( 512/64, 512/64, L_), 256, 0, stream>>>(proj_w, projT, 512, 512);
  transpose_k<<<dim3(2048/64, 512/64, L_), 256, 0, stream>>>(fc1_w,  fc1T, 512, 2048);
  transpose_k<<<dim3( 512/64,2048/64, L_), 256, 0, stream>>>(fc2_w,  fc2T, 2048, 512);
  transpose_k<<<dim3(V_/64,   512/64, 1 ), 256, 0, stream>>>(out_w,  outT, 512, V_);

  embed_k<<<M_, 128, 0, stream>>>(ids, tok, pos, x);

  for(int l = 0; l < L_; l++){
    ln_k<<<M_, 128, 0, stream>>>(x, ln1_g + l*E_, h);
    gemm_bf_k<128><<<(M_/128)*(1536/128), 256, 0, stream>>>(
        h, qkvT + (long long)l*1536*512, qkv_b + l*1536, nullptr, qkvb,
        M_, 1536, E_, 0, 1);
    fattn_k<<<(B_*H_) * (S_/64), 256, 0, stream>>>(qkvb, h);
    gemm_bf_k<64><<<(M_/128)*(512/64), 256, 0, stream>>>(
        h, projT + (long long)l*512*512, proj_b + l*E_, x, x,
        M_, E_, E_, 0, 0);
    ln_k<<<M_, 128, 0, stream>>>(x, ln2_g + l*E_, h);
    gemm_bf_k<128><<<(M_/128)*(2048/128), 256, 0, stream>>>(
        h, fc1T + (long long)l*2048*512, fc1_b + l*2048, nullptr, f1,
        M_, 2048, E_, 1, 1);
    gemm_bf_k<64><<<(M_/128)*(512/64), 256, 0, stream>>>(
        f1, fc2T + (long long)l*512*2048, fc2_b + l*E_, x, x,
        M_, E_, 2048, 0, 0);
  }

  ln_k<<<M_, 128, 0, stream>>>(x, lnf_g, h);
  gemm_bf_k<128><<<(M_/128)*(V_/128), 256, 0, stream>>>(
      h, outT, nullptr, nullptr, logits,
      M_, V_, E_, 0, 0);
}